// Round 4
// baseline (431.675 us; speedup 1.0000x reference)
//
#include <hip/hip_runtime.h>

// Embedding gather: out[r, :] = table[idx[r], :]
// rows = BATCH*NUM_FEATS = 819200, D = 64 floats (256 B) per row.
//
// v5: WARM-SWEEP + gather.
//  Evidence (R3 rocprof): harness re-poisons ~1 GB every iteration at
//  6.4 TB/s -> Infinity Cache (256 MB) is flushed each iteration, so the
//  gather does COLD random 256 B reads from HBM (~1-2 TB/s wall). MLP
//  unroll and NT stores were neutral -> not latency- or thrash-bound;
//  random-DRAM-bound.
//  Fix: sequential sweep of the 256 MB table first (streams at 6.3 TB/s,
//  ~40 us) to allocate it into the memory-side Infinity Cache; the
//  gather's random reads then hit L3. NT stores on `out` (210 MB stream)
//  are kept so the write stream does not evict the warmed table.

#define LANES_PER_ROW 16  // EMBED_DIM * 4 bytes / 16 bytes per lane

typedef float floatx4 __attribute__((ext_vector_type(4)));  // native vec

// Kernel 1: stream the whole table through the caches (allocate in L3).
__global__ __launch_bounds__(256) void warm_table(
    const floatx4* __restrict__ table, long long n_vec)
{
    long long stride = (long long)gridDim.x * blockDim.x;
    for (long long i = (long long)blockIdx.x * blockDim.x + threadIdx.x;
         i < n_vec; i += stride) {
        floatx4 v = table[i];
        // keep the load alive without storing anything
        asm volatile("" :: "v"(v.x), "v"(v.y), "v"(v.z), "v"(v.w));
    }
}

// Kernel 2: the gather (v4 structure: 4-row unroll, NT out stores).
__global__ __launch_bounds__(256) void hh_embed_gather(
    const int* __restrict__ idx,
    const floatx4* __restrict__ table,  // table as 16B vecs: V x 16
    floatx4* __restrict__ out,          // out as 16B vecs:  rows x 16
    int n_rows, int quarter_rows)
{
    int tid  = blockIdx.x * blockDim.x + threadIdx.x;
    int row0 = tid >> 4;        // / LANES_PER_ROW
    int lane = tid & 15;        // % LANES_PER_ROW
    if (row0 >= quarter_rows) return;
    int row1 = row0 + quarter_rows;
    int row2 = row1 + quarter_rows;
    int row3 = row2 + quarter_rows;
    bool has1 = (row1 < n_rows);
    bool has2 = (row2 < n_rows);
    bool has3 = (row3 < n_rows);

    int t0 = idx[row0];
    int t1 = has1 ? idx[row1] : 0;
    int t2 = has2 ? idx[row2] : 0;
    int t3 = has3 ? idx[row3] : 0;

    // Four independent gathers; after the warm sweep these should be
    // Infinity-Cache hits, not DRAM.
    floatx4 v0 = table[(long long)t0 * LANES_PER_ROW + lane];
    floatx4 v1 = table[(long long)t1 * LANES_PER_ROW + lane];
    floatx4 v2 = table[(long long)t2 * LANES_PER_ROW + lane];
    floatx4 v3 = table[(long long)t3 * LANES_PER_ROW + lane];

    // out: write-once stream -> non-temporal, must NOT evict the warmed
    // table from L3.
    __builtin_nontemporal_store(v0, out + (long long)row0 * LANES_PER_ROW + lane);
    if (has1) __builtin_nontemporal_store(v1, out + (long long)row1 * LANES_PER_ROW + lane);
    if (has2) __builtin_nontemporal_store(v2, out + (long long)row2 * LANES_PER_ROW + lane);
    if (has3) __builtin_nontemporal_store(v3, out + (long long)row3 * LANES_PER_ROW + lane);
}

extern "C" void kernel_launch(void* const* d_in, const int* in_sizes, int n_in,
                              void* d_out, int out_size, void* d_ws, size_t ws_size,
                              hipStream_t stream) {
    const int*   idx   = (const int*)d_in[0];     // [B*F] int32
    const float* table = (const float*)d_in[1];   // [V, 64] fp32
    float*       out   = (float*)d_out;           // [B*F, 64] fp32

    int n_rows = in_sizes[0];                     // 819200
    long long table_floats = (long long)in_sizes[1];  // V * 64
    long long n_vec = table_floats / 4;           // # of 16B vectors

    // 1) warm the table into Infinity Cache: 2048 blocks x 256 thr,
    //    grid-stride, ~31 float4 per thread, pure streaming read.
    warm_table<<<2048, 256, 0, stream>>>((const floatx4*)table, n_vec);

    // 2) gather
    int quarter_rows = (n_rows + 3) / 4;
    long long total_threads = (long long)quarter_rows * LANES_PER_ROW;
    int block = 256;
    int grid  = (int)((total_threads + block - 1) / block);
    hh_embed_gather<<<grid, block, 0, stream>>>(
        idx, (const floatx4*)table, (floatx4*)out, n_rows, quarter_rows);
}